// Round 2
// baseline (697.711 us; speedup 1.0000x reference)
//
#include <hip/hip_runtime.h>
#include <hip/hip_bf16.h>

typedef __hip_bfloat16 bf16;
typedef __bf16  bf16x8 __attribute__((ext_vector_type(8)));
typedef float   f32x4  __attribute__((ext_vector_type(4)));

// Problem constants (B=256, L=64, D=1024, H=16, HD=64, HG=8, HDG=128)
#define BL    16384   // B*L rows
#define DDIM  1024
#define NREL  65      // 2*MAXREL+1

#define GLOBAL_AS(p) ((const __attribute__((address_space(1))) void*)(p))
#define LDS_AS(p)    ((__attribute__((address_space(3))) void*)(p))

#define MFMA16(a, b, c) __builtin_amdgcn_mfma_f32_16x16x32_bf16((a), (b), (c), 0, 0, 0)

// ---------------------------------------------------------------------------
// fp32 -> bf16 conversion, 4 elems/thread, vectorized
// ---------------------------------------------------------------------------
__global__ __launch_bounds__(256) void cvt_f32_bf16(const float* __restrict__ in,
                                                    bf16* __restrict__ out, int n)
{
    int i = (blockIdx.x * 256 + threadIdx.x) * 4;
    if (i >= n) return;
    float4 v = *(const float4*)(in + i);
    union { bf16 h[4]; uint2 u; } o;
    o.h[0] = __float2bfloat16(v.x);
    o.h[1] = __float2bfloat16(v.y);
    o.h[2] = __float2bfloat16(v.z);
    o.h[3] = __float2bfloat16(v.w);
    *(uint2*)(out + i) = o.u;
}

// out = 0.7*a + 0.3*b  (bf16 -> bf16)
__global__ __launch_bounds__(256) void blend_kernel(const bf16* __restrict__ a,
                                                    const bf16* __restrict__ b,
                                                    bf16* __restrict__ out, int n)
{
    int i = (blockIdx.x * 256 + threadIdx.x) * 4;
    if (i >= n) return;
    union { bf16 h[4]; uint2 u; } ua, ub, o;
    ua.u = *(const uint2*)(a + i);
    ub.u = *(const uint2*)(b + i);
#pragma unroll
    for (int k = 0; k < 4; ++k)
        o.h[k] = __float2bfloat16(0.7f * __bfloat162float(ua.h[k]) +
                                  0.3f * __bfloat162float(ub.h[k]));
    *(uint2*)(out + i) = o.u;
}

// ---------------------------------------------------------------------------
// 256x256-tile, BK=64, 8-wave (2Mx4N) MFMA GEMM.
// Fine-phase schedule (m201-style): 4 phases per K-tile, each
//   {4-8 ds_read_b128 -> setprio(1) 16xMFMA setprio(0) -> barrier}.
// Counted-vmcnt ledger: prologue stages tiles 0,1 (16 loads). Iter t:
//   vmcnt(8) -> tile t landed (newest 8 = tile t+1); phases read buf[t&1]
//   only; post-ph4 barrier (MFMAs consumed reads => lgkm drained) frees the
//   buffer; stage tile t+2 into buf[t&1]. Last iter: vmcnt(0).
// LDS XOR swizzle (T2) on both stage-source and ds_read. XCD swizzle (T1).
// "Fused" column split: blocks with colBase < NSPLIT use {W0,bias0,C0},
// else {W1,bias1,C1} with column offset colBase-NSPLIT. ldc = NSPLIT.
// ---------------------------------------------------------------------------
template <typename TC>
__global__ __launch_bounds__(512, 2) void gemm256(
    const bf16* __restrict__ A,
    const bf16* __restrict__ W0, const bf16* __restrict__ W1,
    const float* __restrict__ bias0, const float* __restrict__ bias1,
    TC* __restrict__ C0, TC* __restrict__ C1,
    int M, int K, int NX, int NSPLIT)
{
    __shared__ __align__(16) char smem[131072];
    bf16* const A0 = (bf16*)smem;
    bf16* const A1 = (bf16*)(smem + 32768);
    bf16* const B0 = (bf16*)(smem + 65536);
    bf16* const B1 = (bf16*)(smem + 98304);

    const int t    = threadIdx.x;
    const int w    = t >> 6;
    const int lane = t & 63;
    const int m    = lane & 15;
    const int g4   = lane >> 4;
    const int wr   = w >> 2;          // 0..1  (M half of the tile)
    const int wcn  = w & 3;           // 0..3  (N quarter of the tile)

    // T1: bijective XCD swizzle (m204 formula)
    const int nwg = gridDim.x;
    const int q8 = nwg >> 3, r8 = nwg & 7;
    const int xcd = blockIdx.x & 7, loc = blockIdx.x >> 3;
    const int wg = (xcd < r8 ? xcd * (q8 + 1) : r8 * (q8 + 1) + (xcd - r8) * q8) + loc;
    const int rowBase = (wg / NX) * 256;
    const int colBase = (wg % NX) * 256;

    const bf16* Wp; const float* bs; TC* Cp; int colW;
    if (colBase < NSPLIT) {
        Wp = W0 + (size_t)colBase * K; bs = bias0 + colBase; Cp = C0; colW = colBase;
    } else {
        Wp = W1 + (size_t)(colBase - NSPLIT) * K;
        bs = bias1 + (colBase - NSPLIT); Cp = C1; colW = colBase - NSPLIT;
    }

    const char* Ab = (const char*)A + (size_t)rowBase * (size_t)(K * 2);
    const char* Wb = (const char*)Wp;
    const int ldb  = K * 2;
    const int rsub = lane >> 3;
    // T2 pre-swizzled global source: phys[r][pc] holds logical[r][pc ^ ((r&7)<<4)]
    const int swz  = ((lane & 7) << 4) ^ (rsub << 4);

    auto stage = [&](bf16* Ad, bf16* Bd, int kt) {
        const int ktb = kt * 128;
#pragma unroll
        for (int s = 0; s < 4; ++s) {
            const int row = w * 32 + s * 8;
            __builtin_amdgcn_global_load_lds(
                GLOBAL_AS(Ab + (size_t)(row + rsub) * ldb + ktb + swz),
                LDS_AS(Ad + row * 64), 16, 0, 0);
        }
#pragma unroll
        for (int s = 0; s < 4; ++s) {
            const int row = w * 32 + s * 8;
            __builtin_amdgcn_global_load_lds(
                GLOBAL_AS(Wb + (size_t)(row + rsub) * ldb + ktb + swz),
                LDS_AS(Bd + row * 64), 16, 0, 0);
        }
    };

    f32x4 acc[8][4] = {};
    const int NT = K >> 6;

    stage(A0, B0, 0);
    stage(A1, B1, 1);

    const int ar0  = wr * 128;
    const int br0  = wcn * 64;
    const int cswz = (m & 7) << 4;    // frag rows are X*16+m -> row&7 == m&7

    for (int tt = 0; tt < NT; ++tt) {
        const char* Ac = (const char*)((tt & 1) ? A1 : A0);
        const char* Bc = (const char*)((tt & 1) ? B1 : B0);
        if (tt < NT - 1) asm volatile("s_waitcnt vmcnt(8)" ::: "memory");
        else             asm volatile("s_waitcnt vmcnt(0)" ::: "memory");
        __builtin_amdgcn_s_barrier();
        __builtin_amdgcn_sched_barrier(0);

        bf16x8 am[4], bk0[4], bk1[4];

        // ---- phase 1: k-slice 0 x M-half 0 x all N (8 reads, 16 MFMA) ----
#pragma unroll
        for (int i = 0; i < 4; ++i)
            am[i]  = *(const bf16x8*)(Ac + (ar0 + i*16 + m) * 128 + ((g4*16) ^ cswz));
#pragma unroll
        for (int j = 0; j < 4; ++j)
            bk0[j] = *(const bf16x8*)(Bc + (br0 + j*16 + m) * 128 + ((g4*16) ^ cswz));
        __builtin_amdgcn_s_setprio(1);
#pragma unroll
        for (int i = 0; i < 4; ++i)
#pragma unroll
            for (int j = 0; j < 4; ++j)
                acc[i][j] = MFMA16(am[i], bk0[j], acc[i][j]);
        __builtin_amdgcn_s_setprio(0);
        __builtin_amdgcn_s_barrier();
        __builtin_amdgcn_sched_barrier(0);

        // ---- phase 2: k-slice 1 x M-half 0 x all N (8 reads, 16 MFMA) ----
#pragma unroll
        for (int i = 0; i < 4; ++i)
            am[i]  = *(const bf16x8*)(Ac + (ar0 + i*16 + m) * 128 + ((64 + g4*16) ^ cswz));
#pragma unroll
        for (int j = 0; j < 4; ++j)
            bk1[j] = *(const bf16x8*)(Bc + (br0 + j*16 + m) * 128 + ((64 + g4*16) ^ cswz));
        __builtin_amdgcn_s_setprio(1);
#pragma unroll
        for (int i = 0; i < 4; ++i)
#pragma unroll
            for (int j = 0; j < 4; ++j)
                acc[i][j] = MFMA16(am[i], bk1[j], acc[i][j]);
        __builtin_amdgcn_s_setprio(0);
        __builtin_amdgcn_s_barrier();
        __builtin_amdgcn_sched_barrier(0);

        // ---- phase 3: k-slice 0 x M-half 1 (4 reads, 16 MFMA; bk0 held) ----
#pragma unroll
        for (int i = 0; i < 4; ++i)
            am[i]  = *(const bf16x8*)(Ac + (ar0 + 64 + i*16 + m) * 128 + ((g4*16) ^ cswz));
        __builtin_amdgcn_s_setprio(1);
#pragma unroll
        for (int i = 0; i < 4; ++i)
#pragma unroll
            for (int j = 0; j < 4; ++j)
                acc[4+i][j] = MFMA16(am[i], bk0[j], acc[4+i][j]);
        __builtin_amdgcn_s_setprio(0);
        __builtin_amdgcn_s_barrier();
        __builtin_amdgcn_sched_barrier(0);

        // ---- phase 4: k-slice 1 x M-half 1 (4 reads, 16 MFMA; bk1 held) ----
#pragma unroll
        for (int i = 0; i < 4; ++i)
            am[i]  = *(const bf16x8*)(Ac + (ar0 + 64 + i*16 + m) * 128 + ((64 + g4*16) ^ cswz));
        __builtin_amdgcn_s_setprio(1);
#pragma unroll
        for (int i = 0; i < 4; ++i)
#pragma unroll
            for (int j = 0; j < 4; ++j)
                acc[4+i][j] = MFMA16(am[i], bk1[j], acc[4+i][j]);
        __builtin_amdgcn_s_setprio(0);

        __builtin_amdgcn_s_barrier();
        __builtin_amdgcn_sched_barrier(0);
        if (tt + 2 < NT) stage((tt & 1) ? A1 : A0, (tt & 1) ? B1 : B0, tt + 2);
    }

    // ---- epilogue ----
    float bv[4];
#pragma unroll
    for (int j = 0; j < 4; ++j) bv[j] = bs[wcn * 64 + j * 16 + m];

    if constexpr (sizeof(TC) == 2) {
        // stage C through LDS -> fully coalesced 512B row segments (no RMW)
        __syncthreads();
        bf16* Cs = (bf16*)smem;
#pragma unroll
        for (int i = 0; i < 8; ++i)
#pragma unroll
            for (int j = 0; j < 4; ++j)
#pragma unroll
                for (int r = 0; r < 4; ++r)
                    Cs[(wr*128 + i*16 + g4*4 + r) * 256 + wcn*64 + j*16 + m] =
                        __float2bfloat16(acc[i][j][r] + bv[j]);
        __syncthreads();
        char* Cb = (char*)Cp + (size_t)rowBase * (size_t)(NSPLIT * 2) + (size_t)colW * 2;
#pragma unroll
        for (int p = 0; p < 16; ++p) {
            const int row = p * 16 + (t >> 5);
            const int cbt = (t & 31) * 16;
            *(uint4*)(Cb + (size_t)row * (size_t)(NSPLIT * 2) + cbt) =
                *(const uint4*)(smem + row * 512 + cbt);
        }
    } else {
        // f32: 16 lanes x 4B = 64B segments, already line-aligned
        float* Cf = (float*)Cp;
#pragma unroll
        for (int j = 0; j < 4; ++j) {
            const int col = colW + wcn*64 + j*16 + m;
#pragma unroll
            for (int i = 0; i < 8; ++i)
#pragma unroll
                for (int r = 0; r < 4; ++r)
                    Cf[(size_t)(rowBase + wr*128 + i*16 + g4*4 + r) * NSPLIT + col] =
                        acc[i][j][r] + bv[j];
        }
    }
}

// ---------------------------------------------------------------------------
// MFMA local attention with relative-position bias. One block per (b,h).
// S = Q.K^T/8 + gather(Q.rel^T);  softmax in registers;  O = P.V
// ---------------------------------------------------------------------------
__global__ __launch_bounds__(256) void local_attn_mfma(
    const bf16* __restrict__ Q, const bf16* __restrict__ K,
    const bf16* __restrict__ V, const float* __restrict__ RelK,
    bf16* __restrict__ Out)
{
    __shared__ __align__(16) bf16 qs[64 * 64];    // A-operand
    __shared__ __align__(16) bf16 ks[64 * 64];    // B-operand
    __shared__ __align__(16) bf16 rs[80 * 64];    // B-operand (rows 65..79 junk, never read back)
    __shared__ __align__(16) bf16 vt[64 * 66];    // V transposed [d][r], stride 66
    __shared__ __align__(16) bf16 qrl[64 * 80];   // Q.rel^T result
    __shared__ __align__(16) bf16 ps[64 * 64];    // softmaxed P

    const int t    = threadIdx.x;
    const int lane = t & 63;
    const int wv   = t >> 6;
    const int m    = lane & 15;
    const int g4   = lane >> 4;
    const int b    = blockIdx.x >> 4;
    const int h    = blockIdx.x & 15;
    const size_t base = (size_t)b * 64 * DDIM + (size_t)h * 64;

    for (int i = t; i < 1024; i += 256) {
        int e = i * 4, l = e >> 6, d = e & 63;
        const size_t g = base + (size_t)l * DDIM + d;
        *(uint2*)(qs + l * 64 + d) = *(const uint2*)(Q + g);
        *(uint2*)(ks + l * 64 + d) = *(const uint2*)(K + g);
        const bf16* vp = V + g;
        vt[(d + 0) * 66 + l] = vp[0];
        vt[(d + 1) * 66 + l] = vp[1];
        vt[(d + 2) * 66 + l] = vp[2];
        vt[(d + 3) * 66 + l] = vp[3];
    }
    for (int i = t; i < NREL * 64; i += 256)
        rs[i] = __float2bfloat16(RelK[i]);
    __syncthreads();

    // ---- QK^T and Q.rel^T (wave wv owns score rows [wv*16, wv*16+16)) ----
    bf16x8 af[2];
    af[0] = *(const bf16x8*)(qs + (wv * 16 + m) * 64 + 0  + g4 * 8);
    af[1] = *(const bf16x8*)(qs + (wv * 16 + m) * 64 + 32 + g4 * 8);
    f32x4 accS[4] = {}, accR[5] = {};
#pragma unroll
    for (int j = 0; j < 4; ++j)
#pragma unroll
        for (int kc = 0; kc < 2; ++kc) {
            bf16x8 bk = *(const bf16x8*)(ks + (j * 16 + m) * 64 + kc * 32 + g4 * 8);
            accS[j] = MFMA16(af[kc], bk, accS[j]);
        }
#pragma unroll
    for (int p = 0; p < 5; ++p)
#pragma unroll
        for (int kc = 0; kc < 2; ++kc) {
            bf16x8 br = *(const bf16x8*)(rs + (p * 16 + m) * 64 + kc * 32 + g4 * 8);
            accR[p] = MFMA16(af[kc], br, accR[p]);
        }
    // QR -> LDS (C-layout: row = wv*16+g4*4+r, col = p*16+m); cols>64 junk, unread
#pragma unroll
    for (int p = 0; p < 5; ++p)
#pragma unroll
        for (int r = 0; r < 4; ++r)
            qrl[(wv * 16 + g4 * 4 + r) * 80 + p * 16 + m] = __float2bfloat16(accR[p][r]);
    __syncthreads();

    // ---- scores + register softmax ----
    float sc[4][4];
#pragma unroll
    for (int j = 0; j < 4; ++j) {
        const int c = j * 16 + m;
#pragma unroll
        for (int r = 0; r < 4; ++r) {
            const int l = wv * 16 + g4 * 4 + r;
            int rel = c - l;
            rel = rel < -32 ? -32 : (rel > 32 ? 32 : rel);
            sc[j][r] = accS[j][r] * 0.125f +
                       __bfloat162float(qrl[l * 80 + rel + 32]);
        }
    }
#pragma unroll
    for (int r = 0; r < 4; ++r) {
        float mx = fmaxf(fmaxf(sc[0][r], sc[1][r]), fmaxf(sc[2][r], sc[3][r]));
        mx = fmaxf(mx, __shfl_xor(mx, 1));
        mx = fmaxf(mx, __shfl_xor(mx, 2));
        mx = fmaxf(mx, __shfl_xor(mx, 4));
        mx = fmaxf(mx, __shfl_xor(mx, 8));
        float s = 0.f;
#pragma unroll
        for (int j = 0; j < 4; ++j) { float e = __expf(sc[j][r] - mx); sc[j][r] = e; s += e; }
        s += __shfl_xor(s, 1); s += __shfl_xor(s, 2);
        s += __shfl_xor(s, 4); s += __shfl_xor(s, 8);
        const float inv = 1.f / s;
#pragma unroll
        for (int j = 0; j < 4; ++j)
            ps[(wv * 16 + g4 * 4 + r) * 64 + j * 16 + m] = __float2bfloat16(sc[j][r] * inv);
    }
    __syncthreads();

    // ---- O = P.V (B-operand = V^T, stride 66, assembled from b32 reads) ----
    bf16x8 pf[2];
    pf[0] = *(const bf16x8*)(ps + (wv * 16 + m) * 64 + 0  + g4 * 8);
    pf[1] = *(const bf16x8*)(ps + (wv * 16 + m) * 64 + 32 + g4 * 8);
    f32x4 accO[4] = {};
#pragma unroll
    for (int j = 0; j < 4; ++j)
#pragma unroll
        for (int kc = 0; kc < 2; ++kc) {
            union { bf16x8 v; unsigned short u[8]; } bu;
            const unsigned short* vp =
                (const unsigned short*)vt + (j * 16 + m) * 66 + kc * 32 + g4 * 8;
#pragma unroll
            for (int c = 0; c < 8; ++c) bu.u[c] = vp[c];
            accO[j] = MFMA16(pf[kc], bu.v, accO[j]);
        }
#pragma unroll
    for (int j = 0; j < 4; ++j)
#pragma unroll
        for (int r = 0; r < 4; ++r)
            Out[base + (size_t)(wv * 16 + g4 * 4 + r) * DDIM + j * 16 + m] =
                __float2bfloat16(accO[j][r]);
}

// ---------------------------------------------------------------------------
// MFMA global attention (8 heads, hd=128). One block per (b,hg), 64 q-rows.
// NOTE: Out may alias Qg (in-place) -> no __restrict__ on those two.
// ---------------------------------------------------------------------------
__global__ __launch_bounds__(256) void global_attn_mfma(
    const bf16* Qg, const bf16* __restrict__ Kg,
    const bf16* __restrict__ Vg, bf16* Out)
{
    __shared__ __align__(16) bf16 qs[64 * 136];
    __shared__ __align__(16) bf16 ks[64 * 136];
    __shared__ __align__(16) bf16 vt[128 * 66];
    __shared__ __align__(16) bf16 ps[64 * 64];

    const int t    = threadIdx.x;
    const int lane = t & 63;
    const int wv   = t >> 6;
    const int m    = lane & 15;
    const int g4   = lane >> 4;
    const int b    = blockIdx.x >> 3;
    const int hg   = blockIdx.x & 7;
    const size_t base = (size_t)b * 64 * DDIM + (size_t)hg * 128;

    for (int i = t; i < 2048; i += 256) {
        int e = i * 4, l = e >> 7, d = e & 127;
        const size_t g = base + (size_t)l * DDIM + d;
        *(uint2*)(qs + l * 136 + d) = *(const uint2*)(Qg + g);
        *(uint2*)(ks + l * 136 + d) = *(const uint2*)(Kg + g);
        const bf16* vp = Vg + g;
        vt[(d + 0) * 66 + l] = vp[0];
        vt[(d + 1) * 66 + l] = vp[1];
        vt[(d + 2) * 66 + l] = vp[2];
        vt[(d + 3) * 66 + l] = vp[3];
    }
    __syncthreads();

    // ---- S = Q.K^T (K=128) ----
    bf16x8 af[4];
#pragma unroll
    for (int kc = 0; kc < 4; ++kc)
        af[kc] = *(const bf16x8*)(qs + (wv * 16 + m) * 136 + kc * 32 + g4 * 8);
    f32x4 accS[4] = {};
#pragma unroll
    for (int j = 0; j < 4; ++j)
#pragma unroll
        for (int kc = 0; kc < 4; ++kc) {
            bf16x8 bk = *(const bf16x8*)(ks + (j * 16 + m) * 136 + kc * 32 + g4 * 8);
            accS[j] = MFMA16(af[kc], bk, accS[j]);
        }

    // ---- register softmax ----
    float sc[4][4];
#pragma unroll
    for (int j = 0; j < 4; ++j)
#pragma unroll
        for (int r = 0; r < 4; ++r)
            sc[j][r] = accS[j][r] * 0.08838834764831845f;
#pragma unroll
    for (int r = 0; r < 4; ++r) {
        float mx = fmaxf(fmaxf(sc[0][r], sc[1][r]), fmaxf(sc[2][r], sc[3][r]));
        mx = fmaxf(mx, __shfl_xor(mx, 1));
        mx = fmaxf(mx, __shfl_xor(mx, 2));
        mx = fmaxf(mx, __shfl_xor(mx, 4));
        mx = fmaxf(mx, __shfl_xor(mx, 8));
        float s = 0.f;
#pragma unroll
        for (int j = 0; j < 4; ++j) { float e = __expf(sc[j][r] - mx); sc[j][r] = e; s += e; }
        s += __shfl_xor(s, 1); s += __shfl_xor(s, 2);
        s += __shfl_xor(s, 4); s += __shfl_xor(s, 8);
        const float inv = 1.f / s;
#pragma unroll
        for (int j = 0; j < 4; ++j)
            ps[(wv * 16 + g4 * 4 + r) * 64 + j * 16 + m] = __float2bfloat16(sc[j][r] * inv);
    }
    __syncthreads();

    // ---- O = P.V (out cols = 128) ----
    bf16x8 pf[2];
    pf[0] = *(const bf16x8*)(ps + (wv * 16 + m) * 64 + 0  + g4 * 8);
    pf[1] = *(const bf16x8*)(ps + (wv * 16 + m) * 64 + 32 + g4 * 8);
    f32x4 accO[8] = {};
#pragma unroll
    for (int j = 0; j < 8; ++j)
#pragma unroll
        for (int kc = 0; kc < 2; ++kc) {
            union { bf16x8 v; unsigned short u[8]; } bu;
            const unsigned short* vp =
                (const unsigned short*)vt + (j * 16 + m) * 66 + kc * 32 + g4 * 8;
#pragma unroll
            for (int c = 0; c < 8; ++c) bu.u[c] = vp[c];
            accO[j] = MFMA16(pf[kc], bu.v, accO[j]);
        }
#pragma unroll
    for (int j = 0; j < 8; ++j)
#pragma unroll
        for (int r = 0; r < 4; ++r)
            Out[base + (size_t)(wv * 16 + g4 * 4 + r) * DDIM + j * 16 + m] =
                __float2bfloat16(accO[j][r]);
}

// ---------------------------------------------------------------------------
extern "C" void kernel_launch(void* const* d_in, const int* in_sizes, int n_in,
                              void* d_out, int out_size, void* d_ws, size_t ws_size,
                              hipStream_t stream)
{
    const float* query   = (const float*)d_in[0];
    const float* key     = (const float*)d_in[1];
    const float* value   = (const float*)d_in[2];
    const float* Wq      = (const float*)d_in[3];
    const float* bq      = (const float*)d_in[4];
    const float* Wk      = (const float*)d_in[5];
    const float* bk      = (const float*)d_in[6];
    const float* Wv      = (const float*)d_in[7];
    const float* bv      = (const float*)d_in[8];
    const float* Wo      = (const float*)d_in[9];
    const float* bo      = (const float*)d_in[10];
    const float* rel_k   = (const float*)d_in[11];
    // d_in[12] = rel_v: unused by the reference
    const float* g_in_w  = (const float*)d_in[13];
    const float* g_in_b  = (const float*)d_in[14];
    const float* g_out_w = (const float*)d_in[15];
    const float* g_out_b = (const float*)d_in[16];

    char* ws = (char*)d_ws;
    const size_t SZ = (size_t)BL * DDIM * sizeof(bf16);   // 32 MiB
    const size_t MM = (size_t)DDIM * DDIM;
    const size_t WB = 8 * MM * sizeof(bf16);              // 16 MiB
    const bool big = ws_size >= 6 * SZ + WB;              // 208 MiB schedule?
    const int nslots = big ? 6 : 5;

    bf16* s0 = (bf16*)(ws + 0 * SZ);
    bf16* s1 = (bf16*)(ws + 1 * SZ);
    bf16* s2 = (bf16*)(ws + 2 * SZ);
    bf16* s3 = (bf16*)(ws + 3 * SZ);
    bf16* s4 = (bf16*)(ws + 4 * SZ);
    bf16* s5 = (bf16*)(ws + 5 * SZ);   // only used when big
    bf16* wb = (bf16*)(ws + nslots * SZ);
    bf16* wgq = wb;
    bf16* wgk = wb + 1 * MM;
    bf16* wgv = wb + 2 * MM;
    bf16* wq  = wb + 3 * MM;
    bf16* wk  = wb + 4 * MM;
    bf16* wvw = wb + 5 * MM;
    bf16* wo  = wb + 6 * MM;
    bf16* wgo = wb + 7 * MM;

    float* out = (float*)d_out;

    dim3 blk(256);
    dim3 blkG(512);
    const int nAct = BL * DDIM;
    dim3 gCvtA(nAct / 1024);
    dim3 gCvtW((int)MM / 1024);
    dim3 gCvtG(3 * (int)MM / 1024);
    dim3 gLocal(256 * 16);
    dim3 gGlobal(256 * 8);
    dim3 gFus(512);   // fused N=2048: (2048/256)*(16384/256)
    dim3 gUnf(256);   // N=1024

    // weight conversions
    cvt_f32_bf16<<<gCvtG, blk, 0, stream>>>(g_in_w, wgq, 3 * (int)MM);
    cvt_f32_bf16<<<gCvtW, blk, 0, stream>>>(Wq, wq, (int)MM);
    cvt_f32_bf16<<<gCvtW, blk, 0, stream>>>(Wk, wk, (int)MM);
    cvt_f32_bf16<<<gCvtW, blk, 0, stream>>>(Wv, wvw, (int)MM);
    cvt_f32_bf16<<<gCvtW, blk, 0, stream>>>(Wo, wo, (int)MM);
    cvt_f32_bf16<<<gCvtW, blk, 0, stream>>>(g_out_w, wgo, (int)MM);

    if (big) {
        // 6-slot schedule, fused global+local projections (per-block W/C split)
        cvt_f32_bf16<<<gCvtA, blk, 0, stream>>>(query, s0, nAct);
        cvt_f32_bf16<<<gCvtA, blk, 0, stream>>>(key,   s1, nAct);
        cvt_f32_bf16<<<gCvtA, blk, 0, stream>>>(value, s2, nAct);

        bf16* vscr = (bf16*)d_out;   // 32 MiB bf16 scratch inside the 64 MiB f32 output

        // Qg -> s3, Ql -> s4
        gemm256<bf16><<<gFus, blkG, 0, stream>>>(s0, wgq, wq,  g_in_b,        bq, s3, s4,
                                                 BL, DDIM, 8, DDIM);
        // Kg -> s5, Kl -> s0 (xq dead)
        gemm256<bf16><<<gFus, blkG, 0, stream>>>(s1, wgk, wk,  g_in_b + 1024, bk, s5, s0,
                                                 BL, DDIM, 8, DDIM);
        // Vg -> d_out scratch, Vl -> s1 (xk dead)
        gemm256<bf16><<<gFus, blkG, 0, stream>>>(s2, wgv, wvw, g_in_b + 2048, bv, vscr, s1,
                                                 BL, DDIM, 8, DDIM);

        global_attn_mfma<<<gGlobal, blk, 0, stream>>>(s3, s5, vscr, s3);      // in-place
        // Gproj -> s5 (Kg dead)
        gemm256<bf16><<<gUnf, blkG, 0, stream>>>(s3, wgo, wgo, g_out_b, g_out_b, s5, s5,
                                                 BL, DDIM, 4, DDIM);

        local_attn_mfma<<<gLocal, blk, 0, stream>>>(s4, s0, s1, rel_k, s2);   // Lout -> s2

        blend_kernel<<<gCvtA, blk, 0, stream>>>(s2, s5, s0, nAct);
        gemm256<float><<<gUnf, blkG, 0, stream>>>(s0, wo, wo, bo, bo, out, out,
                                                  BL, DDIM, 4, DDIM);
    } else {
        // 5-slot fallback (176 MiB), unfused
        cvt_f32_bf16<<<gCvtA, blk, 0, stream>>>(query, s0, nAct);
        gemm256<bf16><<<gUnf, blkG, 0, stream>>>(s0, wgq, wgq, g_in_b, g_in_b, s1, s1,
                                                 BL, DDIM, 4, DDIM);
        cvt_f32_bf16<<<gCvtA, blk, 0, stream>>>(key, s0, nAct);
        gemm256<bf16><<<gUnf, blkG, 0, stream>>>(s0, wgk, wgk, g_in_b + 1024, g_in_b + 1024,
                                                 s2, s2, BL, DDIM, 4, DDIM);
        cvt_f32_bf16<<<gCvtA, blk, 0, stream>>>(value, s0, nAct);
        gemm256<bf16><<<gUnf, blkG, 0, stream>>>(s0, wgv, wgv, g_in_b + 2048, g_in_b + 2048,
                                                 s3, s3, BL, DDIM, 4, DDIM);

        global_attn_mfma<<<gGlobal, blk, 0, stream>>>(s1, s2, s3, s4);
        gemm256<bf16><<<gUnf, blkG, 0, stream>>>(s4, wgo, wgo, g_out_b, g_out_b, s1, s1,
                                                 BL, DDIM, 4, DDIM);

        cvt_f32_bf16<<<gCvtA, blk, 0, stream>>>(query, s0, nAct);
        gemm256<bf16><<<gUnf, blkG, 0, stream>>>(s0, wq, wq, bq, bq, s2, s2,
                                                 BL, DDIM, 4, DDIM);
        cvt_f32_bf16<<<gCvtA, blk, 0, stream>>>(key, s0, nAct);
        gemm256<bf16><<<gUnf, blkG, 0, stream>>>(s0, wk, wk, bk, bk, s3, s3,
                                                 BL, DDIM, 4, DDIM);
        cvt_f32_bf16<<<gCvtA, blk, 0, stream>>>(value, s0, nAct);
        gemm256<bf16><<<gUnf, blkG, 0, stream>>>(s0, wvw, wvw, bv, bv, s4, s4,
                                                 BL, DDIM, 4, DDIM);

        local_attn_mfma<<<gLocal, blk, 0, stream>>>(s2, s3, s4, rel_k, s0);

        blend_kernel<<<gCvtA, blk, 0, stream>>>(s0, s1, s2, nAct);
        gemm256<float><<<gUnf, blkG, 0, stream>>>(s2, wo, wo, bo, bo, out, out,
                                                  BL, DDIM, 4, DDIM);
    }
}

// Round 3
// 674.371 us; speedup vs baseline: 1.0346x; 1.0346x over previous
//
#include <hip/hip_runtime.h>
#include <hip/hip_bf16.h>

typedef __hip_bfloat16 bf16;
typedef __bf16  bf16x8 __attribute__((ext_vector_type(8)));
typedef float   f32x4  __attribute__((ext_vector_type(4)));

// Problem constants (B=256, L=64, D=1024, H=16, HD=64, HG=8, HDG=128)
#define BL    16384   // B*L rows
#define DDIM  1024
#define NREL  65      // 2*MAXREL+1

#define GLOBAL_AS(p) ((const __attribute__((address_space(1))) void*)(p))
#define LDS_AS(p)    ((__attribute__((address_space(3))) void*)(p))

#define MFMA16(a, b, c) __builtin_amdgcn_mfma_f32_16x16x32_bf16((a), (b), (c), 0, 0, 0)
#define SB0() __builtin_amdgcn_sched_barrier(0)

// ---------------------------------------------------------------------------
// fp32 -> bf16 conversion, 4 elems/thread, vectorized
// ---------------------------------------------------------------------------
__global__ __launch_bounds__(256) void cvt_f32_bf16(const float* __restrict__ in,
                                                    bf16* __restrict__ out, int n)
{
    int i = (blockIdx.x * 256 + threadIdx.x) * 4;
    if (i >= n) return;
    float4 v = *(const float4*)(in + i);
    union { bf16 h[4]; uint2 u; } o;
    o.h[0] = __float2bfloat16(v.x);
    o.h[1] = __float2bfloat16(v.y);
    o.h[2] = __float2bfloat16(v.z);
    o.h[3] = __float2bfloat16(v.w);
    *(uint2*)(out + i) = o.u;
}

// out = 0.7*a + 0.3*b  (bf16 -> bf16)
__global__ __launch_bounds__(256) void blend_kernel(const bf16* __restrict__ a,
                                                    const bf16* __restrict__ b,
                                                    bf16* __restrict__ out, int n)
{
    int i = (blockIdx.x * 256 + threadIdx.x) * 4;
    if (i >= n) return;
    union { bf16 h[4]; uint2 u; } ua, ub, o;
    ua.u = *(const uint2*)(a + i);
    ub.u = *(const uint2*)(b + i);
#pragma unroll
    for (int k = 0; k < 4; ++k)
        o.h[k] = __float2bfloat16(0.7f * __bfloat162float(ua.h[k]) +
                                  0.3f * __bfloat162float(ub.h[k]));
    *(uint2*)(out + i) = o.u;
}

// ---------------------------------------------------------------------------
// 256x256-tile, BK=64, 8-wave (2Mx4N) MFMA GEMM.
// Intra-tile software pipeline, 1 barrier per K-tile:
//   phases P1(m0n0) P2(m0n1) P3(m1n1) P4(m1n0); fragment ds_reads for phase
//   p+1 are issued BEFORE the MFMA cluster of phase p (sched_barrier(0)
//   pinned; compiler emits counted lgkmcnt). Phases of one tile read the
//   SAME LDS buffer -> no intra-tile barriers; waves skew freely, so LDS
//   service overlaps the MFMA pipe (and setprio/T5 has roles to arbitrate).
// Staging: 8 global_load_lds for tile t+1 scattered into the read gaps of
//   tile t (writes buf[(t+1)&1], whose readers finished at tile t-1's
//   barrier -> no WAR). End of tile t: vmcnt(0) [cheap: >1500cyc slack] +
//   s_barrier = (a) all waves' reads of buf[t&1] serviced before tile t+1
//   stages over it, (b) buf[(t+1)&1] published.
// LDS XOR swizzle (T2) on both stage-source and ds_read. XCD swizzle (T1).
// "Fused" column split: blocks with colBase < NSPLIT use {W0,bias0,C0},
// else {W1,bias1,C1} with column offset colBase-NSPLIT. ldc = NSPLIT.
// ---------------------------------------------------------------------------
template <typename TC>
__global__ __launch_bounds__(512, 2) void gemm256(
    const bf16* __restrict__ A,
    const bf16* __restrict__ W0, const bf16* __restrict__ W1,
    const float* __restrict__ bias0, const float* __restrict__ bias1,
    TC* __restrict__ C0, TC* __restrict__ C1,
    int M, int K, int NX, int NSPLIT)
{
    __shared__ __align__(16) char smem[131072];
    bf16* const A0 = (bf16*)smem;
    bf16* const A1 = (bf16*)(smem + 32768);
    bf16* const B0 = (bf16*)(smem + 65536);
    bf16* const B1 = (bf16*)(smem + 98304);

    const int t    = threadIdx.x;
    const int w    = t >> 6;
    const int lane = t & 63;
    const int m    = lane & 15;
    const int g4   = lane >> 4;
    const int wr   = w >> 2;          // 0..1  (M half of the tile)
    const int wcn  = w & 3;           // 0..3  (N quarter of the tile)

    // T1: bijective XCD swizzle (m204 formula)
    const int nwg = gridDim.x;
    const int q8 = nwg >> 3, r8 = nwg & 7;
    const int xcd = blockIdx.x & 7, loc = blockIdx.x >> 3;
    const int wg = (xcd < r8 ? xcd * (q8 + 1) : r8 * (q8 + 1) + (xcd - r8) * q8) + loc;
    const int rowBase = (wg / NX) * 256;
    const int colBase = (wg % NX) * 256;

    const bf16* Wp; const float* bs; TC* Cp; int colW;
    if (colBase < NSPLIT) {
        Wp = W0 + (size_t)colBase * K; bs = bias0 + colBase; Cp = C0; colW = colBase;
    } else {
        Wp = W1 + (size_t)(colBase - NSPLIT) * K;
        bs = bias1 + (colBase - NSPLIT); Cp = C1; colW = colBase - NSPLIT;
    }

    const char* Ab = (const char*)A + (size_t)rowBase * (size_t)(K * 2);
    const char* Wb = (const char*)Wp;
    const int ldb  = K * 2;
    const int rsub = lane >> 3;
    // T2 pre-swizzled global source: phys[r][pc] holds logical[r][pc ^ ((r&7)<<4)]
    const int swz  = ((lane & 7) << 4) ^ (rsub << 4);

    // one quarter of a tile-stage: 1 A-gload + 1 B-gload (x512 threads = 16KB)
    auto stagePart = [&](bf16* Ad, bf16* Bd, int kt, int s) {
        const int ktb = kt * 128;
        const int row = w * 32 + s * 8;
        __builtin_amdgcn_global_load_lds(
            GLOBAL_AS(Ab + (size_t)(row + rsub) * ldb + ktb + swz),
            LDS_AS(Ad + row * 64), 16, 0, 0);
        __builtin_amdgcn_global_load_lds(
            GLOBAL_AS(Wb + (size_t)(row + rsub) * ldb + ktb + swz),
            LDS_AS(Bd + row * 64), 16, 0, 0);
    };

    f32x4 acc[8][4] = {};
    const int NT = K >> 6;

    // prologue: stage tile 0 only; tile 1 is staged during tile 0's body
#pragma unroll
    for (int s = 0; s < 4; ++s) stagePart(A0, B0, 0, s);
    asm volatile("s_waitcnt vmcnt(0)" ::: "memory");
    __builtin_amdgcn_s_barrier();
    SB0();

    const int ar0  = wr * 128;
    const int br0  = wcn * 64;
    const int cswz = (m & 7) << 4;    // frag rows are X*16+m -> row&7 == m&7

    for (int tt = 0; tt < NT; ++tt) {
        const char* Ac = (const char*)((tt & 1) ? A1 : A0);
        const char* Bc = (const char*)((tt & 1) ? B1 : B0);
        bf16* const nAd = (tt & 1) ? A0 : A1;
        bf16* const nBd = (tt & 1) ? B0 : B1;
        const bool pf = (tt + 1 < NT);

        bf16x8 a0[4][2], a1[4][2], b0[2][2], b1[2][2], b0b[2][2];

        // ---- R_P1: A(m0) 8 + B(n0) 4 reads;  + stage part 0 ----
#pragma unroll
        for (int i = 0; i < 4; ++i)
#pragma unroll
            for (int k = 0; k < 2; ++k)
                a0[i][k] = *(const bf16x8*)(Ac + (ar0 + i*16 + m) * 128 +
                                            ((k*64 + g4*16) ^ cswz));
#pragma unroll
        for (int j = 0; j < 2; ++j)
#pragma unroll
            for (int k = 0; k < 2; ++k)
                b0[j][k] = *(const bf16x8*)(Bc + (br0 + j*16 + m) * 128 +
                                            ((k*64 + g4*16) ^ cswz));
        if (pf) stagePart(nAd, nBd, tt + 1, 0);

        // ---- R_P2: B(n1) 4 reads; + stage part 1 ----
#pragma unroll
        for (int j = 0; j < 2; ++j)
#pragma unroll
            for (int k = 0; k < 2; ++k)
                b1[j][k] = *(const bf16x8*)(Bc + (br0 + (j+2)*16 + m) * 128 +
                                            ((k*64 + g4*16) ^ cswz));
        if (pf) stagePart(nAd, nBd, tt + 1, 1);
        SB0();

        // ---- M_P1: (m0,n0) 16 MFMA ----
        __builtin_amdgcn_s_setprio(1);
#pragma unroll
        for (int i = 0; i < 4; ++i)
#pragma unroll
            for (int j = 0; j < 2; ++j)
#pragma unroll
                for (int k = 0; k < 2; ++k)
                    acc[i][j] = MFMA16(a0[i][k], b0[j][k], acc[i][j]);
        __builtin_amdgcn_s_setprio(0);
        SB0();

        // ---- R_P3: A(m1) 8 reads; + stage part 2 ----
#pragma unroll
        for (int i = 0; i < 4; ++i)
#pragma unroll
            for (int k = 0; k < 2; ++k)
                a1[i][k] = *(const bf16x8*)(Ac + (ar0 + 64 + i*16 + m) * 128 +
                                            ((k*64 + g4*16) ^ cswz));
        if (pf) stagePart(nAd, nBd, tt + 1, 2);
        SB0();

        // ---- M_P2: (m0,n1) 16 MFMA ----
        __builtin_amdgcn_s_setprio(1);
#pragma unroll
        for (int i = 0; i < 4; ++i)
#pragma unroll
            for (int j = 0; j < 2; ++j)
#pragma unroll
                for (int k = 0; k < 2; ++k)
                    acc[i][j+2] = MFMA16(a0[i][k], b1[j][k], acc[i][j+2]);
        __builtin_amdgcn_s_setprio(0);
        SB0();

        // ---- R_P4: B(n0) re-read 4; + stage part 3 ----
#pragma unroll
        for (int j = 0; j < 2; ++j)
#pragma unroll
            for (int k = 0; k < 2; ++k)
                b0b[j][k] = *(const bf16x8*)(Bc + (br0 + j*16 + m) * 128 +
                                             ((k*64 + g4*16) ^ cswz));
        if (pf) stagePart(nAd, nBd, tt + 1, 3);
        SB0();

        // ---- M_P3: (m1,n1) 16 MFMA ----
        __builtin_amdgcn_s_setprio(1);
#pragma unroll
        for (int i = 0; i < 4; ++i)
#pragma unroll
            for (int j = 0; j < 2; ++j)
#pragma unroll
                for (int k = 0; k < 2; ++k)
                    acc[4+i][j+2] = MFMA16(a1[i][k], b1[j][k], acc[4+i][j+2]);
        __builtin_amdgcn_s_setprio(0);
        SB0();

        // ---- M_P4: (m1,n0) 16 MFMA ----
        __builtin_amdgcn_s_setprio(1);
#pragma unroll
        for (int i = 0; i < 4; ++i)
#pragma unroll
            for (int j = 0; j < 2; ++j)
#pragma unroll
                for (int k = 0; k < 2; ++k)
                    acc[4+i][j] = MFMA16(a1[i][k], b0b[j][k], acc[4+i][j]);
        __builtin_amdgcn_s_setprio(0);

        // ---- tile boundary: drain own stage loads (cheap) + single barrier ----
        if (pf) {
            asm volatile("s_waitcnt vmcnt(0)" ::: "memory");
            __builtin_amdgcn_s_barrier();
            SB0();
        }
    }

    // ---- epilogue ----
    float bv[4];
#pragma unroll
    for (int j = 0; j < 4; ++j) bv[j] = bs[wcn * 64 + j * 16 + m];

    if constexpr (sizeof(TC) == 2) {
        // stage C through LDS -> fully coalesced 512B row segments (no RMW)
        __syncthreads();
        bf16* Cs = (bf16*)smem;
#pragma unroll
        for (int i = 0; i < 8; ++i)
#pragma unroll
            for (int j = 0; j < 4; ++j)
#pragma unroll
                for (int r = 0; r < 4; ++r)
                    Cs[(wr*128 + i*16 + g4*4 + r) * 256 + wcn*64 + j*16 + m] =
                        __float2bfloat16(acc[i][j][r] + bv[j]);
        __syncthreads();
        char* Cb = (char*)Cp + (size_t)rowBase * (size_t)(NSPLIT * 2) + (size_t)colW * 2;
#pragma unroll
        for (int p = 0; p < 16; ++p) {
            const int row = p * 16 + (t >> 5);
            const int cbt = (t & 31) * 16;
            *(uint4*)(Cb + (size_t)row * (size_t)(NSPLIT * 2) + cbt) =
                *(const uint4*)(smem + row * 512 + cbt);
        }
    } else {
        // f32: 16 lanes x 4B = 64B segments, already line-aligned
        float* Cf = (float*)Cp;
#pragma unroll
        for (int j = 0; j < 4; ++j) {
            const int col = colW + wcn*64 + j*16 + m;
#pragma unroll
            for (int i = 0; i < 8; ++i)
#pragma unroll
                for (int r = 0; r < 4; ++r)
                    Cf[(size_t)(rowBase + wr*128 + i*16 + g4*4 + r) * NSPLIT + col] =
                        acc[i][j][r] + bv[j];
        }
    }
}

// ---------------------------------------------------------------------------
// MFMA local attention with relative-position bias. One block per (b,h).
// S = Q.K^T/8 + gather(Q.rel^T);  softmax in registers;  O = P.V
// ---------------------------------------------------------------------------
__global__ __launch_bounds__(256) void local_attn_mfma(
    const bf16* __restrict__ Q, const bf16* __restrict__ K,
    const bf16* __restrict__ V, const float* __restrict__ RelK,
    bf16* __restrict__ Out)
{
    __shared__ __align__(16) bf16 qs[64 * 64];    // A-operand
    __shared__ __align__(16) bf16 ks[64 * 64];    // B-operand
    __shared__ __align__(16) bf16 rs[80 * 64];    // B-operand (rows 65..79 junk, never read back)
    __shared__ __align__(16) bf16 vt[64 * 66];    // V transposed [d][r], stride 66
    __shared__ __align__(16) bf16 qrl[64 * 80];   // Q.rel^T result
    __shared__ __align__(16) bf16 ps[64 * 64];    // softmaxed P

    const int t    = threadIdx.x;
    const int lane = t & 63;
    const int wv   = t >> 6;
    const int m    = lane & 15;
    const int g4   = lane >> 4;
    const int b    = blockIdx.x >> 4;
    const int h    = blockIdx.x & 15;
    const size_t base = (size_t)b * 64 * DDIM + (size_t)h * 64;

    for (int i = t; i < 1024; i += 256) {
        int e = i * 4, l = e >> 6, d = e & 63;
        const size_t g = base + (size_t)l * DDIM + d;
        *(uint2*)(qs + l * 64 + d) = *(const uint2*)(Q + g);
        *(uint2*)(ks + l * 64 + d) = *(const uint2*)(K + g);
        const bf16* vp = V + g;
        vt[(d + 0) * 66 + l] = vp[0];
        vt[(d + 1) * 66 + l] = vp[1];
        vt[(d + 2) * 66 + l] = vp[2];
        vt[(d + 3) * 66 + l] = vp[3];
    }
    for (int i = t; i < NREL * 64; i += 256)
        rs[i] = __float2bfloat16(RelK[i]);
    __syncthreads();

    // ---- QK^T and Q.rel^T (wave wv owns score rows [wv*16, wv*16+16)) ----
    bf16x8 af[2];
    af[0] = *(const bf16x8*)(qs + (wv * 16 + m) * 64 + 0  + g4 * 8);
    af[1] = *(const bf16x8*)(qs + (wv * 16 + m) * 64 + 32 + g4 * 8);
    f32x4 accS[4] = {}, accR[5] = {};
#pragma unroll
    for (int j = 0; j < 4; ++j)
#pragma unroll
        for (int kc = 0; kc < 2; ++kc) {
            bf16x8 bk = *(const bf16x8*)(ks + (j * 16 + m) * 64 + kc * 32 + g4 * 8);
            accS[j] = MFMA16(af[kc], bk, accS[j]);
        }
#pragma unroll
    for (int p = 0; p < 5; ++p)
#pragma unroll
        for (int kc = 0; kc < 2; ++kc) {
            bf16x8 br = *(const bf16x8*)(rs + (p * 16 + m) * 64 + kc * 32 + g4 * 8);
            accR[p] = MFMA16(af[kc], br, accR[p]);
        }
    // QR -> LDS (C-layout: row = wv*16+g4*4+r, col = p*16+m); cols>64 junk, unread
#pragma unroll
    for (int p = 0; p < 5; ++p)
#pragma unroll
        for (int r = 0; r < 4; ++r)
            qrl[(wv * 16 + g4 * 4 + r) * 80 + p * 16 + m] = __float2bfloat16(accR[p][r]);
    __syncthreads();

    // ---- scores + register softmax ----
    float sc[4][4];
#pragma unroll
    for (int j = 0; j < 4; ++j) {
        const int c = j * 16 + m;
#pragma unroll
        for (int r = 0; r < 4; ++r) {
            const int l = wv * 16 + g4 * 4 + r;
            int rel = c - l;
            rel = rel < -32 ? -32 : (rel > 32 ? 32 : rel);
            sc[j][r] = accS[j][r] * 0.125f +
                       __bfloat162float(qrl[l * 80 + rel + 32]);
        }
    }
#pragma unroll
    for (int r = 0; r < 4; ++r) {
        float mx = fmaxf(fmaxf(sc[0][r], sc[1][r]), fmaxf(sc[2][r], sc[3][r]));
        mx = fmaxf(mx, __shfl_xor(mx, 1));
        mx = fmaxf(mx, __shfl_xor(mx, 2));
        mx = fmaxf(mx, __shfl_xor(mx, 4));
        mx = fmaxf(mx, __shfl_xor(mx, 8));
        float s = 0.f;
#pragma unroll
        for (int j = 0; j < 4; ++j) { float e = __expf(sc[j][r] - mx); sc[j][r] = e; s += e; }
        s += __shfl_xor(s, 1); s += __shfl_xor(s, 2);
        s += __shfl_xor(s, 4); s += __shfl_xor(s, 8);
        const float inv = 1.f / s;
#pragma unroll
        for (int j = 0; j < 4; ++j)
            ps[(wv * 16 + g4 * 4 + r) * 64 + j * 16 + m] = __float2bfloat16(sc[j][r] * inv);
    }
    __syncthreads();

    // ---- O = P.V (B-operand = V^T, stride 66, assembled from b32 reads) ----
    bf16x8 pf[2];
    pf[0] = *(const bf16x8*)(ps + (wv * 16 + m) * 64 + 0  + g4 * 8);
    pf[1] = *(const bf16x8*)(ps + (wv * 16 + m) * 64 + 32 + g4 * 8);
    f32x4 accO[4] = {};
#pragma unroll
    for (int j = 0; j < 4; ++j)
#pragma unroll
        for (int kc = 0; kc < 2; ++kc) {
            union { bf16x8 v; unsigned short u[8]; } bu;
            const unsigned short* vp =
                (const unsigned short*)vt + (j * 16 + m) * 66 + kc * 32 + g4 * 8;
#pragma unroll
            for (int c = 0; c < 8; ++c) bu.u[c] = vp[c];
            accO[j] = MFMA16(pf[kc], bu.v, accO[j]);
        }
#pragma unroll
    for (int j = 0; j < 4; ++j)
#pragma unroll
        for (int r = 0; r < 4; ++r)
            Out[base + (size_t)(wv * 16 + g4 * 4 + r) * DDIM + j * 16 + m] =
                __float2bfloat16(accO[j][r]);
}

// ---------------------------------------------------------------------------
// MFMA global attention (8 heads, hd=128). One block per (b,hg), 64 q-rows.
// NOTE: Out may alias Qg (in-place) -> no __restrict__ on those two.
// ---------------------------------------------------------------------------
__global__ __launch_bounds__(256) void global_attn_mfma(
    const bf16* Qg, const bf16* __restrict__ Kg,
    const bf16* __restrict__ Vg, bf16* Out)
{
    __shared__ __align__(16) bf16 qs[64 * 136];
    __shared__ __align__(16) bf16 ks[64 * 136];
    __shared__ __align__(16) bf16 vt[128 * 66];
    __shared__ __align__(16) bf16 ps[64 * 64];

    const int t    = threadIdx.x;
    const int lane = t & 63;
    const int wv   = t >> 6;
    const int m    = lane & 15;
    const int g4   = lane >> 4;
    const int b    = blockIdx.x >> 3;
    const int hg   = blockIdx.x & 7;
    const size_t base = (size_t)b * 64 * DDIM + (size_t)hg * 128;

    for (int i = t; i < 2048; i += 256) {
        int e = i * 4, l = e >> 7, d = e & 127;
        const size_t g = base + (size_t)l * DDIM + d;
        *(uint2*)(qs + l * 136 + d) = *(const uint2*)(Qg + g);
        *(uint2*)(ks + l * 136 + d) = *(const uint2*)(Kg + g);
        const bf16* vp = Vg + g;
        vt[(d + 0) * 66 + l] = vp[0];
        vt[(d + 1) * 66 + l] = vp[1];
        vt[(d + 2) * 66 + l] = vp[2];
        vt[(d + 3) * 66 + l] = vp[3];
    }
    __syncthreads();

    // ---- S = Q.K^T (K=128) ----
    bf16x8 af[4];
#pragma unroll
    for (int kc = 0; kc < 4; ++kc)
        af[kc] = *(const bf16x8*)(qs + (wv * 16 + m) * 136 + kc * 32 + g4 * 8);
    f32x4 accS[4] = {};
#pragma unroll
    for (int j = 0; j < 4; ++j)
#pragma unroll
        for (int kc = 0; kc < 4; ++kc) {
            bf16x8 bk = *(const bf16x8*)(ks + (j * 16 + m) * 136 + kc * 32 + g4 * 8);
            accS[j] = MFMA16(af[kc], bk, accS[j]);
        }

    // ---- register softmax ----
    float sc[4][4];
#pragma unroll
    for (int j = 0; j < 4; ++j)
#pragma unroll
        for (int r = 0; r < 4; ++r)
            sc[j][r] = accS[j][r] * 0.08838834764831845f;
#pragma unroll
    for (int r = 0; r < 4; ++r) {
        float mx = fmaxf(fmaxf(sc[0][r], sc[1][r]), fmaxf(sc[2][r], sc[3][r]));
        mx = fmaxf(mx, __shfl_xor(mx, 1));
        mx = fmaxf(mx, __shfl_xor(mx, 2));
        mx = fmaxf(mx, __shfl_xor(mx, 4));
        mx = fmaxf(mx, __shfl_xor(mx, 8));
        float s = 0.f;
#pragma unroll
        for (int j = 0; j < 4; ++j) { float e = __expf(sc[j][r] - mx); sc[j][r] = e; s += e; }
        s += __shfl_xor(s, 1); s += __shfl_xor(s, 2);
        s += __shfl_xor(s, 4); s += __shfl_xor(s, 8);
        const float inv = 1.f / s;
#pragma unroll
        for (int j = 0; j < 4; ++j)
            ps[(wv * 16 + g4 * 4 + r) * 64 + j * 16 + m] = __float2bfloat16(sc[j][r] * inv);
    }
    __syncthreads();

    // ---- O = P.V (out cols = 128) ----
    bf16x8 pf[2];
    pf[0] = *(const bf16x8*)(ps + (wv * 16 + m) * 64 + 0  + g4 * 8);
    pf[1] = *(const bf16x8*)(ps + (wv * 16 + m) * 64 + 32 + g4 * 8);
    f32x4 accO[8] = {};
#pragma unroll
    for (int j = 0; j < 8; ++j)
#pragma unroll
        for (int kc = 0; kc < 2; ++kc) {
            union { bf16x8 v; unsigned short u[8]; } bu;
            const unsigned short* vp =
                (const unsigned short*)vt + (j * 16 + m) * 66 + kc * 32 + g4 * 8;
#pragma unroll
            for (int c = 0; c < 8; ++c) bu.u[c] = vp[c];
            accO[j] = MFMA16(pf[kc], bu.v, accO[j]);
        }
#pragma unroll
    for (int j = 0; j < 8; ++j)
#pragma unroll
        for (int r = 0; r < 4; ++r)
            Out[base + (size_t)(wv * 16 + g4 * 4 + r) * DDIM + j * 16 + m] =
                __float2bfloat16(accO[j][r]);
}

// ---------------------------------------------------------------------------
extern "C" void kernel_launch(void* const* d_in, const int* in_sizes, int n_in,
                              void* d_out, int out_size, void* d_ws, size_t ws_size,
                              hipStream_t stream)
{
    const float* query   = (const float*)d_in[0];
    const float* key     = (const float*)d_in[1];
    const float* value   = (const float*)d_in[2];
    const float* Wq      = (const float*)d_in[3];
    const float* bq      = (const float*)d_in[4];
    const float* Wk      = (const float*)d_in[5];
    const float* bk      = (const float*)d_in[6];
    const float* Wv      = (const float*)d_in[7];
    const float* bv      = (const float*)d_in[8];
    const float* Wo      = (const float*)d_in[9];
    const float* bo      = (const float*)d_in[10];
    const float* rel_k   = (const float*)d_in[11];
    // d_in[12] = rel_v: unused by the reference
    const float* g_in_w  = (const float*)d_in[13];
    const float* g_in_b  = (const float*)d_in[14];
    const float* g_out_w = (const float*)d_in[15];
    const float* g_out_b = (const float*)d_in[16];

    char* ws = (char*)d_ws;
    const size_t SZ = (size_t)BL * DDIM * sizeof(bf16);   // 32 MiB
    const size_t MM = (size_t)DDIM * DDIM;
    const size_t WB = 8 * MM * sizeof(bf16);              // 16 MiB
    const bool big = ws_size >= 6 * SZ + WB;              // 208 MiB schedule?
    const int nslots = big ? 6 : 5;

    bf16* s0 = (bf16*)(ws + 0 * SZ);
    bf16* s1 = (bf16*)(ws + 1 * SZ);
    bf16* s2 = (bf16*)(ws + 2 * SZ);
    bf16* s3 = (bf16*)(ws + 3 * SZ);
    bf16* s4 = (bf16*)(ws + 4 * SZ);
    bf16* s5 = (bf16*)(ws + 5 * SZ);   // only used when big
    bf16* wb = (bf16*)(ws + nslots * SZ);
    bf16* wgq = wb;
    bf16* wgk = wb + 1 * MM;
    bf16* wgv = wb + 2 * MM;
    bf16* wq  = wb + 3 * MM;
    bf16* wk  = wb + 4 * MM;
    bf16* wvw = wb + 5 * MM;
    bf16* wo  = wb + 6 * MM;
    bf16* wgo = wb + 7 * MM;

    float* out = (float*)d_out;

    dim3 blk(256);
    dim3 blkG(512);
    const int nAct = BL * DDIM;
    dim3 gCvtA(nAct / 1024);
    dim3 gCvtW((int)MM / 1024);
    dim3 gCvtG(3 * (int)MM / 1024);
    dim3 gLocal(256 * 16);
    dim3 gGlobal(256 * 8);
    dim3 gFus(512);   // fused N=2048: (2048/256)*(16384/256)
    dim3 gUnf(256);   // N=1024

    // weight conversions
    cvt_f32_bf16<<<gCvtG, blk, 0, stream>>>(g_in_w, wgq, 3 * (int)MM);
    cvt_f32_bf16<<<gCvtW, blk, 0, stream>>>(Wq, wq, (int)MM);
    cvt_f32_bf16<<<gCvtW, blk, 0, stream>>>(Wk, wk, (int)MM);
    cvt_f32_bf16<<<gCvtW, blk, 0, stream>>>(Wv, wvw, (int)MM);
    cvt_f32_bf16<<<gCvtW, blk, 0, stream>>>(Wo, wo, (int)MM);
    cvt_f32_bf16<<<gCvtW, blk, 0, stream>>>(g_out_w, wgo, (int)MM);

    if (big) {
        // 6-slot schedule, fused global+local projections (per-block W/C split)
        cvt_f32_bf16<<<gCvtA, blk, 0, stream>>>(query, s0, nAct);
        cvt_f32_bf16<<<gCvtA, blk, 0, stream>>>(key,   s1, nAct);
        cvt_f32_bf16<<<gCvtA, blk, 0, stream>>>(value, s2, nAct);

        bf16* vscr = (bf16*)d_out;   // 32 MiB bf16 scratch inside the 64 MiB f32 output

        // Qg -> s3, Ql -> s4
        gemm256<bf16><<<gFus, blkG, 0, stream>>>(s0, wgq, wq,  g_in_b,        bq, s3, s4,
                                                 BL, DDIM, 8, DDIM);
        // Kg -> s5, Kl -> s0 (xq dead)
        gemm256<bf16><<<gFus, blkG, 0, stream>>>(s1, wgk, wk,  g_in_b + 1024, bk, s5, s0,
                                                 BL, DDIM, 8, DDIM);
        // Vg -> d_out scratch, Vl -> s1 (xk dead)
        gemm256<bf16><<<gFus, blkG, 0, stream>>>(s2, wgv, wvw, g_in_b + 2048, bv, vscr, s1,
                                                 BL, DDIM, 8, DDIM);

        global_attn_mfma<<<gGlobal, blk, 0, stream>>>(s3, s5, vscr, s3);      // in-place
        // Gproj -> s5 (Kg dead)
        gemm256<bf16><<<gUnf, blkG, 0, stream>>>(s3, wgo, wgo, g_out_b, g_out_b, s5, s5,
                                                 BL, DDIM, 4, DDIM);

        local_attn_mfma<<<gLocal, blk, 0, stream>>>(s4, s0, s1, rel_k, s2);   // Lout -> s2

        blend_kernel<<<gCvtA, blk, 0, stream>>>(s2, s5, s0, nAct);
        gemm256<float><<<gUnf, blkG, 0, stream>>>(s0, wo, wo, bo, bo, out, out,
                                                  BL, DDIM, 4, DDIM);
    } else {
        // 5-slot fallback (176 MiB), unfused
        cvt_f32_bf16<<<gCvtA, blk, 0, stream>>>(query, s0, nAct);
        gemm256<bf16><<<gUnf, blkG, 0, stream>>>(s0, wgq, wgq, g_in_b, g_in_b, s1, s1,
                                                 BL, DDIM, 4, DDIM);
        cvt_f32_bf16<<<gCvtA, blk, 0, stream>>>(key, s0, nAct);
        gemm256<bf16><<<gUnf, blkG, 0, stream>>>(s0, wgk, wgk, g_in_b + 1024, g_in_b + 1024,
                                                 s2, s2, BL, DDIM, 4, DDIM);
        cvt_f32_bf16<<<gCvtA, blk, 0, stream>>>(value, s0, nAct);
        gemm256<bf16><<<gUnf, blkG, 0, stream>>>(s0, wgv, wgv, g_in_b + 2048, g_in_b + 2048,
                                                 s3, s3, BL, DDIM, 4, DDIM);

        global_attn_mfma<<<gGlobal, blk, 0, stream>>>(s1, s2, s3, s4);
        gemm256<bf16><<<gUnf, blkG, 0, stream>>>(s4, wgo, wgo, g_out_b, g_out_b, s1, s1,
                                                 BL, DDIM, 4, DDIM);

        cvt_f32_bf16<<<gCvtA, blk, 0, stream>>>(query, s0, nAct);
        gemm256<bf16><<<gUnf, blkG, 0, stream>>>(s0, wq, wq, bq, bq, s2, s2,
                                                 BL, DDIM, 4, DDIM);
        cvt_f32_bf16<<<gCvtA, blk, 0, stream>>>(key, s0, nAct);
        gemm256<bf16><<<gUnf, blkG, 0, stream>>>(s0, wk, wk, bk, bk, s3, s3,
                                                 BL, DDIM, 4, DDIM);
        cvt_f32_bf16<<<gCvtA, blk, 0, stream>>>(value, s0, nAct);
        gemm256<bf16><<<gUnf, blkG, 0, stream>>>(s0, wvw, wvw, bv, bv, s4, s4,
                                                 BL, DDIM, 4, DDIM);

        local_attn_mfma<<<gLocal, blk, 0, stream>>>(s2, s3, s4, rel_k, s0);

        blend_kernel<<<gCvtA, blk, 0, stream>>>(s0, s1, s2, nAct);
        gemm256<float><<<gUnf, blkG, 0, stream>>>(s2, wo, wo, bo, bo, out, out,
                                                  BL, DDIM, 4, DDIM);
    }
}